// Round 1
// baseline (302.522 us; speedup 1.0000x reference)
//
#include <hip/hip_runtime.h>

typedef __attribute__((ext_vector_type(8))) short bf16x8;
typedef __attribute__((ext_vector_type(4))) float f32x4;
typedef unsigned short u16;

__device__ __forceinline__ float bf2f(u16 u) {
  union { unsigned int i; float f; } c; c.i = ((unsigned int)u) << 16; return c.f;
}
__device__ __forceinline__ u16 f2bf(float f) {
  union { float f; unsigned int i; } c; c.f = f;
  unsigned int u = c.i;
  unsigned int r = (u + 0x7FFFu + ((u >> 16) & 1u)) >> 16;  // RNE
  return (u16)r;
}

// ---------------- CSR / normalization build ----------------

__global__ void k_init_deg(int* deg, int n) {
  int i = blockIdx.x * 256 + threadIdx.x;
  if (i < n) deg[i] = 1;  // self-loop
}

__global__ void k_count(const int* __restrict__ ei, int* deg, int E) {
  int e = blockIdx.x * 256 + threadIdx.x;
  if (e < E) atomicAdd(&deg[ei[E + e]], 1);  // dst = edge_index[1][e]
}

__global__ void k_blocksum(const int* __restrict__ deg, int* bsum, int n) {
  __shared__ int s[256];
  int t = threadIdx.x;
  int i = blockIdx.x * 256 + t;
  s[t] = (i < n) ? (deg[i] - 1) : 0;  // CSR holds only real edges
  __syncthreads();
  for (int o = 128; o > 0; o >>= 1) {
    if (t < o) s[t] += s[t + o];
    __syncthreads();
  }
  if (t == 0) bsum[blockIdx.x] = s[0];
}

__global__ void k_scanb(const int* __restrict__ bsum, int* bofs, int nb) {
  // single block of 256, nb <= 256
  __shared__ int s[256];
  int t = threadIdx.x;
  int v = (t < nb) ? bsum[t] : 0;
  s[t] = v;
  __syncthreads();
  for (int o = 1; o < 256; o <<= 1) {
    int x = (t >= o) ? s[t - o] : 0;
    __syncthreads();
    s[t] += x;
    __syncthreads();
  }
  bofs[t] = s[t] - v;  // exclusive
}

__global__ void k_rowptr(const int* __restrict__ deg, const int* __restrict__ bofs,
                         int* rowptr, int* cursor, float* dinv, int n) {
  __shared__ int s[256];
  int t = threadIdx.x;
  int i = blockIdx.x * 256 + t;
  int d = (i < n) ? deg[i] : 1;
  int v = (i < n) ? (d - 1) : 0;
  s[t] = v;
  __syncthreads();
  for (int o = 1; o < 256; o <<= 1) {
    int x = (t >= o) ? s[t - o] : 0;
    __syncthreads();
    s[t] += x;
    __syncthreads();
  }
  int excl = s[t] - v + bofs[blockIdx.x];
  if (i < n) {
    rowptr[i] = excl;
    cursor[i] = excl;
    dinv[i] = rsqrtf((float)d);
    if (i == n - 1) rowptr[n] = excl + v;
  }
}

__global__ void k_fill(const int* __restrict__ ei, int* cursor, int* col, int E) {
  int e = blockIdx.x * 256 + threadIdx.x;
  if (e >= E) return;
  int s = ei[e];        // src
  int d = ei[E + e];    // dst
  int pos = atomicAdd(&cursor[d], 1);
  col[pos] = s;
}

// transpose + bf16 convert weights: W[K][N] f32 -> Wt[N][K] bf16
__global__ void k_twt(const float* __restrict__ W, u16* __restrict__ Wt, int K, int N) {
  int i = blockIdx.x * 256 + threadIdx.x;
  if (i >= K * N) return;
  int k = i / N, n = i - k * N;
  Wt[n * K + k] = f2bf(W[i]);
}

// ---------------- GEMM: C[M,ldc] (bf16) = A[M,K] @ Bt[ldc,K]^T ----------------
// 128x128 tile, 4 waves (each 64x64 = 4x4 frags of 16x16), BK=32, reg-prefetch.

template <bool AF32, int K>
__launch_bounds__(256)
__global__ void gemm_kernel(const void* __restrict__ Ap, const u16* __restrict__ Bt,
                            u16* __restrict__ C, int M, int ldc) {
  __shared__ u16 As[128][40];  // 40: pad to break bank conflicts; 80B stride keeps 16B align
  __shared__ u16 Bs[128][40];
  const int tid = threadIdx.x;
  const int lane = tid & 63;
  const int wid = tid >> 6;
  const int wr = wid >> 1, wc = wid & 1;
  const long brow = (long)blockIdx.x * 128;
  const long bcol = (long)blockIdx.y * 128;
  const int srow = tid >> 1;       // 0..127: tile row staged by this thread
  const int kb = (tid & 1) << 4;   // 0 or 16: k-offset within BK=32

  f32x4 acc[4][4];
#pragma unroll
  for (int i = 0; i < 4; i++)
#pragma unroll
    for (int j = 0; j < 4; j++) acc[i][j] = (f32x4){0.f, 0.f, 0.f, 0.f};

  union Pack { u16 s[16]; uint4 v[2]; };
  Pack pa, pb;
  constexpr int NT = K / 32;

  auto stage = [&](int kt) {
    const long rgA = brow + srow;
    if constexpr (AF32) {
      const float* A = (const float*)Ap;
      if (rgA < M) {
        const float4* p = (const float4*)(A + rgA * (long)K + kt * 32 + kb);
#pragma unroll
        for (int i = 0; i < 4; i++) {
          float4 v = p[i];
          pa.s[4 * i + 0] = f2bf(v.x);
          pa.s[4 * i + 1] = f2bf(v.y);
          pa.s[4 * i + 2] = f2bf(v.z);
          pa.s[4 * i + 3] = f2bf(v.w);
        }
      } else {
#pragma unroll
        for (int i = 0; i < 16; i++) pa.s[i] = 0;
      }
    } else {
      const u16* A = (const u16*)Ap;
      const uint4* p = (const uint4*)(A + rgA * (long)K + kt * 32 + kb);
      pa.v[0] = p[0];
      pa.v[1] = p[1];
    }
    const uint4* q = (const uint4*)(Bt + (bcol + srow) * (long)K + kt * 32 + kb);
    pb.v[0] = q[0];
    pb.v[1] = q[1];
  };

  stage(0);
  for (int kt = 0; kt < NT; ++kt) {
    __syncthreads();
    *(uint4*)&As[srow][kb] = pa.v[0];
    *(uint4*)&As[srow][kb + 8] = pa.v[1];
    *(uint4*)&Bs[srow][kb] = pb.v[0];
    *(uint4*)&Bs[srow][kb + 8] = pb.v[1];
    __syncthreads();
    if (kt + 1 < NT) stage(kt + 1);

    bf16x8 af[4], bf[4];
#pragma unroll
    for (int i = 0; i < 4; i++)
      af[i] = *(const bf16x8*)&As[wr * 64 + i * 16 + (lane & 15)][(lane >> 4) * 8];
#pragma unroll
    for (int j = 0; j < 4; j++)
      bf[j] = *(const bf16x8*)&Bs[wc * 64 + j * 16 + (lane & 15)][(lane >> 4) * 8];
#pragma unroll
    for (int i = 0; i < 4; i++)
#pragma unroll
      for (int j = 0; j < 4; j++)
        acc[i][j] = __builtin_amdgcn_mfma_f32_16x16x32_bf16(af[i], bf[j], acc[i][j], 0, 0, 0);
  }

#pragma unroll
  for (int i = 0; i < 4; i++) {
    const long r0 = brow + wr * 64 + i * 16 + ((lane >> 4) * 4);
#pragma unroll
    for (int j = 0; j < 4; j++) {
      const long cc = bcol + wc * 64 + j * 16 + (lane & 15);
#pragma unroll
      for (int q = 0; q < 4; q++) {
        long r = r0 + q;
        if (r < M) C[r * (long)ldc + cc] = f2bf(acc[i][j][q]);
      }
    }
  }
}

// ---------------- Aggregation (one wave per node) ----------------
// out[dst,:] = dinv[dst] * ( sum_{e: src->dst} dinv[src]*h[src,:] + dinv[dst]*h[dst,:] ) + b

__launch_bounds__(256)
__global__ void agg1(const u16* __restrict__ h0, const int* __restrict__ rowptr,
                     const int* __restrict__ col, const float* __restrict__ dinv,
                     const float* __restrict__ b1, u16* __restrict__ h, int n) {
  const int wid = threadIdx.x >> 6, lane = threadIdx.x & 63;
  const int node = blockIdx.x * 4 + wid;
  if (node >= n) return;
  const float di = dinv[node];
  ushort4 sv = ((const ushort4*)(h0 + (size_t)node * 256))[lane];
  float a0 = di * bf2f(sv.x), a1 = di * bf2f(sv.y), a2 = di * bf2f(sv.z), a3 = di * bf2f(sv.w);
  int e = rowptr[node];
  const int r1 = rowptr[node + 1];
  for (; e + 4 <= r1; e += 4) {
    int s0 = col[e], s1 = col[e + 1], s2 = col[e + 2], s3 = col[e + 3];
    float c0 = dinv[s0], c1 = dinv[s1], c2 = dinv[s2], c3 = dinv[s3];
    ushort4 v0 = ((const ushort4*)(h0 + (size_t)s0 * 256))[lane];
    ushort4 v1 = ((const ushort4*)(h0 + (size_t)s1 * 256))[lane];
    ushort4 v2 = ((const ushort4*)(h0 + (size_t)s2 * 256))[lane];
    ushort4 v3 = ((const ushort4*)(h0 + (size_t)s3 * 256))[lane];
    a0 += c0 * bf2f(v0.x) + c1 * bf2f(v1.x) + c2 * bf2f(v2.x) + c3 * bf2f(v3.x);
    a1 += c0 * bf2f(v0.y) + c1 * bf2f(v1.y) + c2 * bf2f(v2.y) + c3 * bf2f(v3.y);
    a2 += c0 * bf2f(v0.z) + c1 * bf2f(v1.z) + c2 * bf2f(v2.z) + c3 * bf2f(v3.z);
    a3 += c0 * bf2f(v0.w) + c1 * bf2f(v1.w) + c2 * bf2f(v2.w) + c3 * bf2f(v3.w);
  }
  for (; e < r1; ++e) {
    int s = col[e];
    float c = dinv[s];
    ushort4 v = ((const ushort4*)(h0 + (size_t)s * 256))[lane];
    a0 += c * bf2f(v.x); a1 += c * bf2f(v.y); a2 += c * bf2f(v.z); a3 += c * bf2f(v.w);
  }
  float4 bb = ((const float4*)b1)[lane];
  a0 = a0 * di + bb.x; a1 = a1 * di + bb.y; a2 = a2 * di + bb.z; a3 = a3 * di + bb.w;
  a0 = a0 > 0.f ? a0 : 0.f; a1 = a1 > 0.f ? a1 : 0.f;
  a2 = a2 > 0.f ? a2 : 0.f; a3 = a3 > 0.f ? a3 : 0.f;
  ushort4 o; o.x = f2bf(a0); o.y = f2bf(a1); o.z = f2bf(a2); o.w = f2bf(a3);
  ((ushort4*)(h + (size_t)node * 256))[lane] = o;
}

__device__ __forceinline__ float sigmoidf_(float x) { return 1.f / (1.f + __expf(-x)); }

__launch_bounds__(256)
__global__ void agg2(const u16* __restrict__ h2, const int* __restrict__ rowptr,
                     const int* __restrict__ col, const float* __restrict__ dinv,
                     const float* __restrict__ b2, float* __restrict__ out, int n) {
  const int wid = threadIdx.x >> 6, lane = threadIdx.x & 63;
  const int node = blockIdx.x * 4 + wid;
  if (node >= n) return;
  const float di = dinv[node];
  ushort2 sv = ((const ushort2*)(h2 + (size_t)node * 128))[lane];
  float a0 = di * bf2f(sv.x), a1 = di * bf2f(sv.y);
  int e = rowptr[node];
  const int r1 = rowptr[node + 1];
  for (; e + 4 <= r1; e += 4) {
    int s0 = col[e], s1 = col[e + 1], s2 = col[e + 2], s3 = col[e + 3];
    float c0 = dinv[s0], c1 = dinv[s1], c2 = dinv[s2], c3 = dinv[s3];
    ushort2 v0 = ((const ushort2*)(h2 + (size_t)s0 * 128))[lane];
    ushort2 v1 = ((const ushort2*)(h2 + (size_t)s1 * 128))[lane];
    ushort2 v2 = ((const ushort2*)(h2 + (size_t)s2 * 128))[lane];
    ushort2 v3 = ((const ushort2*)(h2 + (size_t)s3 * 128))[lane];
    a0 += c0 * bf2f(v0.x) + c1 * bf2f(v1.x) + c2 * bf2f(v2.x) + c3 * bf2f(v3.x);
    a1 += c0 * bf2f(v0.y) + c1 * bf2f(v1.y) + c2 * bf2f(v2.y) + c3 * bf2f(v3.y);
  }
  for (; e < r1; ++e) {
    int s = col[e];
    float c = dinv[s];
    ushort2 v = ((const ushort2*)(h2 + (size_t)s * 128))[lane];
    a0 += c * bf2f(v.x); a1 += c * bf2f(v.y);
  }
  float2 bb = ((const float2*)b2)[lane];
  float2 o;
  o.x = sigmoidf_(a0 * di + bb.x);
  o.y = sigmoidf_(a1 * di + bb.y);
  ((float2*)(out + (size_t)node * 128))[lane] = o;
}

// ---------------- launch ----------------

extern "C" void kernel_launch(void* const* d_in, const int* in_sizes, int n_in,
                              void* d_out, int out_size, void* d_ws, size_t ws_size,
                              hipStream_t stream) {
  const float* x  = (const float*)d_in[0];
  const float* W1 = (const float*)d_in[1];
  const float* b1 = (const float*)d_in[2];
  const float* W2 = (const float*)d_in[3];
  const float* b2 = (const float*)d_in[4];
  const int*   ei = (const int*)d_in[5];

  const int N = in_sizes[0] / 512;
  const int E = in_sizes[5] / 2;
  const int Mpad = (N + 127) & ~127;
  float* outp = (float*)d_out;

  char* w = (char*)d_ws;
  size_t off = 0;
  auto take = [&](size_t bytes) -> void* {
    void* p = w + off;
    off = (off + bytes + 255) & ~(size_t)255;
    return p;
  };
  u16*   h0     = (u16*)take((size_t)Mpad * 256 * 2);
  u16*   hb     = (u16*)take((size_t)Mpad * 256 * 2);
  u16*   h2     = (u16*)take((size_t)Mpad * 128 * 2);
  u16*   W1t    = (u16*)take(256 * 512 * 2);
  u16*   W2t    = (u16*)take(128 * 256 * 2);
  int*   deg    = (int*)take((size_t)N * 4);
  float* dinv   = (float*)take((size_t)N * 4);
  int*   rowptr = (int*)take((size_t)(N + 1) * 4);
  int*   cursor = (int*)take((size_t)N * 4);
  int*   colx   = (int*)take((size_t)E * 4);
  int*   bsum   = (int*)take(256 * 4);
  int*   bofs   = (int*)take(256 * 4);
  (void)ws_size; (void)n_in; (void)out_size;

  const int nb = (N + 255) / 256;      // 196 <= 256 (required by k_scanb)
  const int eb = (E + 255) / 256;

  k_init_deg<<<nb, 256, 0, stream>>>(deg, N);
  k_count<<<eb, 256, 0, stream>>>(ei, deg, E);
  k_blocksum<<<nb, 256, 0, stream>>>(deg, bsum, N);
  k_scanb<<<1, 256, 0, stream>>>(bsum, bofs, nb);
  k_rowptr<<<nb, 256, 0, stream>>>(deg, bofs, rowptr, cursor, dinv, N);
  k_fill<<<eb, 256, 0, stream>>>(ei, cursor, colx, E);
  k_twt<<<(512 * 256 + 255) / 256, 256, 0, stream>>>(W1, W1t, 512, 256);
  k_twt<<<(256 * 128 + 255) / 256, 256, 0, stream>>>(W2, W2t, 256, 128);

  dim3 g1(Mpad / 128, 2);
  gemm_kernel<true, 512><<<g1, 256, 0, stream>>>((const void*)x, W1t, h0, N, 256);
  agg1<<<(N + 3) / 4, 256, 0, stream>>>(h0, rowptr, colx, dinv, b1, hb, N);
  dim3 g2(Mpad / 128, 1);
  gemm_kernel<false, 256><<<g2, 256, 0, stream>>>((const void*)hb, W2t, h2, Mpad, 128);
  agg2<<<(N + 3) / 4, 256, 0, stream>>>(h2, rowptr, colx, dinv, b2, outp, N);
}

// Round 2
// 251.885 us; speedup vs baseline: 1.2010x; 1.2010x over previous
//
#include <hip/hip_runtime.h>
#include <type_traits>

typedef __attribute__((ext_vector_type(8))) short bf16x8;
typedef __attribute__((ext_vector_type(4))) float f32x4;
typedef unsigned short u16;
typedef unsigned int u32;
typedef __attribute__((address_space(1))) const u32 gu32;
typedef __attribute__((address_space(3))) u32 lu32;

__device__ __forceinline__ float bf2f(u16 u) {
  union { u32 i; float f; } c; c.i = ((u32)u) << 16; return c.f;
}
__device__ __forceinline__ u16 f2bf(float f) {
  union { float f; u32 i; } c; c.f = f;
  u32 u = c.i;
  u32 r = (u + 0x7FFFu + ((u >> 16) & 1u)) >> 16;  // RNE
  return (u16)r;
}

// async 16B global->LDS (linear dest: wave-uniform base + lane*16)
__device__ __forceinline__ void gld16(const void* g, void* l) {
  __builtin_amdgcn_global_load_lds((gu32*)g, (lu32*)l, 16, 0, 0);
}

// ---------------- CSR / normalization build ----------------

__global__ void k_init_deg(int* deg, int n) {
  int i = blockIdx.x * 256 + threadIdx.x;
  if (i < n) deg[i] = 1;  // self-loop
}

__global__ void k_count(const int* __restrict__ ei, int* deg, int E) {
  int e = blockIdx.x * 256 + threadIdx.x;
  if (e < E) atomicAdd(&deg[ei[E + e]], 1);  // dst = edge_index[1][e]
}

__global__ void k_blocksum(const int* __restrict__ deg, int* bsum, int n) {
  __shared__ int s[256];
  int t = threadIdx.x;
  int i = blockIdx.x * 256 + t;
  s[t] = (i < n) ? (deg[i] - 1) : 0;
  __syncthreads();
  for (int o = 128; o > 0; o >>= 1) {
    if (t < o) s[t] += s[t + o];
    __syncthreads();
  }
  if (t == 0) bsum[blockIdx.x] = s[0];
}

__global__ void k_scanb(const int* __restrict__ bsum, int* bofs, int nb) {
  __shared__ int s[256];
  int t = threadIdx.x;
  int v = (t < nb) ? bsum[t] : 0;
  s[t] = v;
  __syncthreads();
  for (int o = 1; o < 256; o <<= 1) {
    int x = (t >= o) ? s[t - o] : 0;
    __syncthreads();
    s[t] += x;
    __syncthreads();
  }
  bofs[t] = s[t] - v;  // exclusive
}

__global__ void k_rowptr(const int* __restrict__ deg, const int* __restrict__ bofs,
                         int* rowptr, int* cursor, float* dinv, int n) {
  __shared__ int s[256];
  int t = threadIdx.x;
  int i = blockIdx.x * 256 + t;
  int d = (i < n) ? deg[i] : 1;
  int v = (i < n) ? (d - 1) : 0;
  s[t] = v;
  __syncthreads();
  for (int o = 1; o < 256; o <<= 1) {
    int x = (t >= o) ? s[t - o] : 0;
    __syncthreads();
    s[t] += x;
    __syncthreads();
  }
  int excl = s[t] - v + bofs[blockIdx.x];
  if (i < n) {
    rowptr[i] = excl;
    cursor[i] = excl;
    dinv[i] = rsqrtf((float)d);
    if (i == n - 1) rowptr[n] = excl + v;
  }
}

// pack (src, dinv[src]) per edge: kills the dependent scattered dinv load in agg
__global__ void k_fill(const int* __restrict__ ei, int* cursor,
                       const float* __restrict__ dinv, int2* colw, int E) {
  int e = blockIdx.x * 256 + threadIdx.x;
  if (e >= E) return;
  int s = ei[e];
  int d = ei[E + e];
  int pos = atomicAdd(&cursor[d], 1);
  colw[pos] = make_int2(s, __float_as_int(dinv[s]));
}

// transpose + bf16 convert weights: W[K][N] f32 -> Wt[N][K] bf16
__global__ void k_twt(const float* __restrict__ W, u16* __restrict__ Wt, int K, int N) {
  int i = blockIdx.x * 256 + threadIdx.x;
  if (i >= K * N) return;
  int k = i / N, n = i - k * N;
  Wt[n * K + k] = f2bf(W[i]);
}

// ---------------- GEMM: C[M,ldc](bf16) = A[M,K] @ Bt[ldc,K]^T ----------------
// 128x128 tile, BK=32, 4 waves (each 64x64), double-buffered global_load_lds,
// XOR-swizzled LDS (pre-swizzled global source + swizzled ds_read).

template <bool AF32, int K>
__launch_bounds__(256)
__global__ void gemm_kernel(const void* __restrict__ Ap, const u16* __restrict__ Bt,
                            u16* __restrict__ C, int M, int ldc) {
  using AT = typename std::conditional<AF32, float, u16>::type;
  // A: 128 rows x 32 k. fp32 row=128B (8x16B units, swz row&7); bf16 row=64B (4 units, swz row&3).
  // Both are 4096 elements per buffer.
  __shared__ AT As_[2][4096];
  __shared__ u16 Bs_[2][4096];  // 128 rows x 32 k bf16 = 8KB per buffer

  const int tid = threadIdx.x;
  const int lane = tid & 63;
  const int wid = tid >> 6;
  const int wr = wid >> 1, wc = wid & 1;
  const long brow = (long)blockIdx.x * 128;
  const long bcol = (long)blockIdx.y * 128;

  constexpr int NT = K / 32;
  constexpr int NJA = AF32 ? 4 : 2;  // A staging issues (4KB each)

  // --- precompute staging pointers (global pre-swizzled, LDS linear) ---
  const AT* agp[NJA];
  AT* alp[NJA];
#pragma unroll
  for (int j = 0; j < NJA; ++j) {
    int idx = j * 256 + tid;  // 16B-unit index within tile
    int row, u;
    if constexpr (AF32) { row = idx >> 3; u = (idx & 7) ^ (row & 7); }
    else                { row = idx >> 2; u = (idx & 3) ^ (row & 3); }
    long grow = brow + row;
    if (grow > (long)M - 1) grow = M - 1;  // clamp: garbage confined to rows>=M, never stored
    agp[j] = (const AT*)Ap + grow * (long)K + u * (AF32 ? 4 : 8);
    alp[j] = &As_[0][idx * (AF32 ? 4 : 8)];
  }
  const u16* bgp[2];
  u16* blp[2];
#pragma unroll
  for (int j = 0; j < 2; ++j) {
    int idx = j * 256 + tid;
    int row = idx >> 2;
    int u = (idx & 3) ^ (row & 3);
    bgp[j] = Bt + (bcol + row) * (long)K + u * 8;
    blp[j] = &Bs_[0][idx * 8];
  }

  f32x4 acc[4][4];
#pragma unroll
  for (int i = 0; i < 4; i++)
#pragma unroll
    for (int j = 0; j < 4; j++) acc[i][j] = (f32x4){0.f, 0.f, 0.f, 0.f};

  auto stage = [&](int kt, int buf) {
    const int boff = buf * 4096;
#pragma unroll
    for (int j = 0; j < NJA; ++j) gld16(agp[j] + kt * 32, alp[j] + boff);
#pragma unroll
    for (int j = 0; j < 2; ++j) gld16(bgp[j] + kt * 32, blp[j] + boff);
  };

  stage(0, 0);
  int cur = 0;
  for (int kt = 0; kt < NT; ++kt) {
    __syncthreads();  // vmcnt(0)+lgkmcnt(0) drain: tile kt resident; all done reading cur^1
    if (kt + 1 < NT) stage(kt + 1, cur ^ 1);  // overlaps with compute below

    bf16x8 af[4], bfq[4];
#pragma unroll
    for (int i = 0; i < 4; i++) {
      const int row = wr * 64 + i * 16 + (lane & 15);
      if constexpr (AF32) {
        const float* bp = (const float*)&As_[cur][0] + row * 32;
        const int s = row & 7;
        const int u0 = (lane >> 4) * 2;
        float4 x0 = *(const float4*)(bp + (u0 ^ s) * 4);
        float4 x1 = *(const float4*)(bp + ((u0 + 1) ^ s) * 4);
        union { u32 w[4]; bf16x8 v; } cv;
        asm("v_cvt_pk_bf16_f32 %0, %1, %2" : "=v"(cv.w[0]) : "v"(x0.x), "v"(x0.y));
        asm("v_cvt_pk_bf16_f32 %0, %1, %2" : "=v"(cv.w[1]) : "v"(x0.z), "v"(x0.w));
        asm("v_cvt_pk_bf16_f32 %0, %1, %2" : "=v"(cv.w[2]) : "v"(x1.x), "v"(x1.y));
        asm("v_cvt_pk_bf16_f32 %0, %1, %2" : "=v"(cv.w[3]) : "v"(x1.z), "v"(x1.w));
        af[i] = cv.v;
      } else {
        const int u = (lane >> 4) ^ (row & 3);
        af[i] = *(const bf16x8*)((const u16*)&As_[cur][0] + row * 32 + u * 8);
      }
    }
#pragma unroll
    for (int j = 0; j < 4; j++) {
      const int row = wc * 64 + j * 16 + (lane & 15);
      const int u = (lane >> 4) ^ (row & 3);
      bfq[j] = *(const bf16x8*)(&Bs_[cur][0] + row * 32 + u * 8);
    }
#pragma unroll
    for (int i = 0; i < 4; i++)
#pragma unroll
      for (int j = 0; j < 4; j++)
        acc[i][j] = __builtin_amdgcn_mfma_f32_16x16x32_bf16(af[i], bfq[j], acc[i][j], 0, 0, 0);
    cur ^= 1;
  }

#pragma unroll
  for (int i = 0; i < 4; i++) {
    const long r0 = brow + wr * 64 + i * 16 + ((lane >> 4) * 4);
#pragma unroll
    for (int j = 0; j < 4; j++) {
      const long cc = bcol + wc * 64 + j * 16 + (lane & 15);
#pragma unroll
      for (int q = 0; q < 4; q++) {
        long r = r0 + q;
        if (r < M) C[r * (long)ldc + cc] = f2bf(acc[i][j][q]);
      }
    }
  }
}

// ---------------- Aggregation (one wave per node) ----------------

__launch_bounds__(256)
__global__ void agg1(const u16* __restrict__ h0, const int* __restrict__ rowptr,
                     const int2* __restrict__ colw, const float* __restrict__ dinv,
                     const float* __restrict__ b1, u16* __restrict__ h, int n) {
  const int wid = threadIdx.x >> 6, lane = threadIdx.x & 63;
  const int node = blockIdx.x * 4 + wid;
  if (node >= n) return;
  const float di = dinv[node];
  ushort4 sv = ((const ushort4*)(h0 + (size_t)node * 256))[lane];
  float a0 = di * bf2f(sv.x), a1 = di * bf2f(sv.y), a2 = di * bf2f(sv.z), a3 = di * bf2f(sv.w);
  int e = rowptr[node];
  const int r1 = rowptr[node + 1];
  for (; e + 4 <= r1; e += 4) {
    int2 c0 = colw[e], c1 = colw[e + 1], c2 = colw[e + 2], c3 = colw[e + 3];
    float w0 = __int_as_float(c0.y), w1 = __int_as_float(c1.y);
    float w2 = __int_as_float(c2.y), w3 = __int_as_float(c3.y);
    ushort4 v0 = ((const ushort4*)(h0 + (size_t)c0.x * 256))[lane];
    ushort4 v1 = ((const ushort4*)(h0 + (size_t)c1.x * 256))[lane];
    ushort4 v2 = ((const ushort4*)(h0 + (size_t)c2.x * 256))[lane];
    ushort4 v3 = ((const ushort4*)(h0 + (size_t)c3.x * 256))[lane];
    a0 += w0 * bf2f(v0.x) + w1 * bf2f(v1.x) + w2 * bf2f(v2.x) + w3 * bf2f(v3.x);
    a1 += w0 * bf2f(v0.y) + w1 * bf2f(v1.y) + w2 * bf2f(v2.y) + w3 * bf2f(v3.y);
    a2 += w0 * bf2f(v0.z) + w1 * bf2f(v1.z) + w2 * bf2f(v2.z) + w3 * bf2f(v3.z);
    a3 += w0 * bf2f(v0.w) + w1 * bf2f(v1.w) + w2 * bf2f(v2.w) + w3 * bf2f(v3.w);
  }
  for (; e < r1; ++e) {
    int2 c = colw[e];
    float wv = __int_as_float(c.y);
    ushort4 v = ((const ushort4*)(h0 + (size_t)c.x * 256))[lane];
    a0 += wv * bf2f(v.x); a1 += wv * bf2f(v.y); a2 += wv * bf2f(v.z); a3 += wv * bf2f(v.w);
  }
  float4 bb = ((const float4*)b1)[lane];
  a0 = a0 * di + bb.x; a1 = a1 * di + bb.y; a2 = a2 * di + bb.z; a3 = a3 * di + bb.w;
  a0 = a0 > 0.f ? a0 : 0.f; a1 = a1 > 0.f ? a1 : 0.f;
  a2 = a2 > 0.f ? a2 : 0.f; a3 = a3 > 0.f ? a3 : 0.f;
  ushort4 o; o.x = f2bf(a0); o.y = f2bf(a1); o.z = f2bf(a2); o.w = f2bf(a3);
  ((ushort4*)(h + (size_t)node * 256))[lane] = o;
}

__device__ __forceinline__ float sigmoidf_(float x) { return 1.f / (1.f + __expf(-x)); }

__launch_bounds__(256)
__global__ void agg2(const u16* __restrict__ h2, const int* __restrict__ rowptr,
                     const int2* __restrict__ colw, const float* __restrict__ dinv,
                     const float* __restrict__ b2, float* __restrict__ out, int n) {
  const int wid = threadIdx.x >> 6, lane = threadIdx.x & 63;
  const int node = blockIdx.x * 4 + wid;
  if (node >= n) return;
  const float di = dinv[node];
  ushort2 sv = ((const ushort2*)(h2 + (size_t)node * 128))[lane];
  float a0 = di * bf2f(sv.x), a1 = di * bf2f(sv.y);
  int e = rowptr[node];
  const int r1 = rowptr[node + 1];
  for (; e + 4 <= r1; e += 4) {
    int2 c0 = colw[e], c1 = colw[e + 1], c2 = colw[e + 2], c3 = colw[e + 3];
    float w0 = __int_as_float(c0.y), w1 = __int_as_float(c1.y);
    float w2 = __int_as_float(c2.y), w3 = __int_as_float(c3.y);
    ushort2 v0 = ((const ushort2*)(h2 + (size_t)c0.x * 128))[lane];
    ushort2 v1 = ((const ushort2*)(h2 + (size_t)c1.x * 128))[lane];
    ushort2 v2 = ((const ushort2*)(h2 + (size_t)c2.x * 128))[lane];
    ushort2 v3 = ((const ushort2*)(h2 + (size_t)c3.x * 128))[lane];
    a0 += w0 * bf2f(v0.x) + w1 * bf2f(v1.x) + w2 * bf2f(v2.x) + w3 * bf2f(v3.x);
    a1 += w0 * bf2f(v0.y) + w1 * bf2f(v1.y) + w2 * bf2f(v2.y) + w3 * bf2f(v3.y);
  }
  for (; e < r1; ++e) {
    int2 c = colw[e];
    float wv = __int_as_float(c.y);
    ushort2 v = ((const ushort2*)(h2 + (size_t)c.x * 128))[lane];
    a0 += wv * bf2f(v.x); a1 += wv * bf2f(v.y);
  }
  float2 bb = ((const float2*)b2)[lane];
  float2 o;
  o.x = sigmoidf_(a0 * di + bb.x);
  o.y = sigmoidf_(a1 * di + bb.y);
  ((float2*)(out + (size_t)node * 128))[lane] = o;
}

// ---------------- launch ----------------

extern "C" void kernel_launch(void* const* d_in, const int* in_sizes, int n_in,
                              void* d_out, int out_size, void* d_ws, size_t ws_size,
                              hipStream_t stream) {
  const float* x  = (const float*)d_in[0];
  const float* W1 = (const float*)d_in[1];
  const float* b1 = (const float*)d_in[2];
  const float* W2 = (const float*)d_in[3];
  const float* b2 = (const float*)d_in[4];
  const int*   ei = (const int*)d_in[5];

  const int N = in_sizes[0] / 512;
  const int E = in_sizes[5] / 2;
  const int Mpad = (N + 127) & ~127;
  float* outp = (float*)d_out;

  char* w = (char*)d_ws;
  size_t off = 0;
  auto take = [&](size_t bytes) -> void* {
    void* p = w + off;
    off = (off + bytes + 255) & ~(size_t)255;
    return p;
  };
  u16*   h0     = (u16*)take((size_t)Mpad * 256 * 2);
  u16*   hb     = (u16*)take((size_t)Mpad * 256 * 2);
  u16*   h2     = (u16*)take((size_t)Mpad * 128 * 2);
  u16*   W1t    = (u16*)take(256 * 512 * 2);
  u16*   W2t    = (u16*)take(128 * 256 * 2);
  int*   deg    = (int*)take((size_t)N * 4);
  float* dinv   = (float*)take((size_t)N * 4);
  int*   rowptr = (int*)take((size_t)(N + 1) * 4);
  int*   cursor = (int*)take((size_t)N * 4);
  int2*  colw   = (int2*)take((size_t)E * 8);
  int*   bsum   = (int*)take(256 * 4);
  int*   bofs   = (int*)take(256 * 4);
  (void)ws_size; (void)n_in; (void)out_size;

  const int nb = (N + 255) / 256;  // <=256 required by k_scanb
  const int eb = (E + 255) / 256;

  k_init_deg<<<nb, 256, 0, stream>>>(deg, N);
  k_count<<<eb, 256, 0, stream>>>(ei, deg, E);
  k_blocksum<<<nb, 256, 0, stream>>>(deg, bsum, N);
  k_scanb<<<1, 256, 0, stream>>>(bsum, bofs, nb);
  k_rowptr<<<nb, 256, 0, stream>>>(deg, bofs, rowptr, cursor, dinv, N);
  k_fill<<<eb, 256, 0, stream>>>(ei, cursor, dinv, colw, E);
  k_twt<<<(512 * 256 + 255) / 256, 256, 0, stream>>>(W1, W1t, 512, 256);
  k_twt<<<(256 * 128 + 255) / 256, 256, 0, stream>>>(W2, W2t, 256, 128);

  dim3 g1(Mpad / 128, 2);
  gemm_kernel<true, 512><<<g1, 256, 0, stream>>>((const void*)x, W1t, h0, N, 256);
  agg1<<<(N + 3) / 4, 256, 0, stream>>>(h0, rowptr, colw, dinv, b1, hb, N);
  dim3 g2(Mpad / 128, 1);
  gemm_kernel<false, 256><<<g2, 256, 0, stream>>>((const void*)hb, W2t, h2, Mpad, 128);
  agg2<<<(N + 3) / 4, 256, 0, stream>>>(h2, rowptr, colw, dinv, b2, outp, N);
}